// Round 11
// baseline (411.573 us; speedup 1.0000x reference)
//
#include <hip/hip_runtime.h>
#include <math.h>

// ws layout (floats):
//   esq   : [4096]
//   state : [64*8192]   f_rest, channel-major [b][c][yx]  (== f layout)
//   fhat  : [64*8192]   [b][c][yx]
//   z     : [16384][32] pair=(v<<6|b) rows
//   keys  : [2][16384] u64 (old psc region) — packed (mono(d)<<32)|j per pair
#define WS_ESQ   0
#define WS_STATE 4096
#define WS_FHAT  (4096 + 524288)
#define WS_Z     (4096 + 2*524288)
#define WS_PSC   (4096 + 3*524288)

__device__ __forceinline__ float4 v4add(float4 a, float4 b) {
    return make_float4(__fadd_rn(a.x,b.x), __fadd_rn(a.y,b.y),
                       __fadd_rn(a.z,b.z), __fadd_rn(a.w,b.w));
}
__device__ __forceinline__ float4 v4sq(float4 a) {
    return make_float4(__fmul_rn(a.x,a.x), __fmul_rn(a.y,a.y),
                       __fmul_rn(a.z,a.z), __fmul_rn(a.w,a.w));
}
// numpy pairwise sum of 32 pre-rounded squares held in 8 float4s
__device__ __forceinline__ float np_pw32(float4 q0, float4 q1, float4 q2, float4 q3,
                                         float4 q4, float4 q5, float4 q6, float4 q7) {
    float4 rA = v4add(v4add(v4add(q0, q2), q4), q6);   // r[0..3]
    float4 rB = v4add(v4add(v4add(q1, q3), q5), q7);   // r[4..7]
    float l = __fadd_rn(__fadd_rn(rA.x, rA.y), __fadd_rn(rA.z, rA.w));
    float h = __fadd_rn(__fadd_rn(rB.x, rB.y), __fadd_rn(rB.z, rB.w));
    return __fadd_rn(l, h);
}

__device__ __forceinline__ double keys64(double x) {
    // jax keys cubic (a=-0.5)
    if (x < 1.0)      return ((1.5*x - 2.5)*x)*x + 1.0;
    else if (x < 2.0) return ((-0.5*x + 2.5)*x - 4.0)*x + 2.0;
    return 0.0;
}

// Apply kernel: 512 WGs = 64 b x 8 channel-slices of 4 (+16 esq WGs at s0).
// Prev-scale argmin read straight from the packed atomic key (low 32 bits).
// Slice-0 WGs init THIS scale's key buffer (double-buffered by s&1).
// All fp32 sequences (bicubic, pool) bit-identical to the validated kernel.
__global__ __launch_bounds__(256) void vq_apply(
    const float* __restrict__ f, const float* __restrict__ emb,
    float* __restrict__ esq, float* __restrict__ state, float* __restrict__ fhat,
    float* __restrict__ zws, const unsigned long long* __restrict__ keysPrev,
    unsigned long long* __restrict__ keysCur,
    int sIdx, int pn, int pnPrev)
{
    __shared__ float fr[1280];      // f_rest slice [yx*5+cc]
    __shared__ float hs[676];       // h slice [v*4+cc]
    __shared__ int   idx_arr[176];
    __shared__ float U[256];        // bicubic weights [out][in], fp64->fp32 like jax

    const int tid = threadIdx.x;
    const int wg  = blockIdx.x;
    if (wg >= 512) {                // s0 only: esq WGs
        int j = ((wg - 512) << 8) + tid;
        const float4* e4 = (const float4*)(emb + (size_t)j*32);
        esq[j] = np_pw32(v4sq(e4[0]),v4sq(e4[1]),v4sq(e4[2]),v4sq(e4[3]),
                         v4sq(e4[4]),v4sq(e4[5]),v4sq(e4[6]),v4sq(e4[7]));
        return;
    }
    const int b  = wg >> 3;
    const int c0 = (wg & 7) * 4;

    // init this scale's keys (slice-0 WG per b); scan launches after apply.
    if ((wg & 7) == 0) {
        const int V = pn * pn;
        for (int v = tid; v < V; v += 256) keysCur[(v << 6) + b] = ~0ull;
    }

    // ---- P1: load f_rest slice (channel-major, coalesced) ----
    const float* src = (sIdx <= 1) ? f : state;      // s0 never writes state: same layout
    for (int o = tid; o < 1024; o += 256) {
        int cc = o >> 8, yx = o & 255;
        fr[yx*5 + cc] = src[b*8192 + (c0 + cc)*256 + yx];
    }
    __syncthreads();

    if (sIdx > 0) {
        const int Vp = pnPrev * pnPrev;
        // ---- P2: read prev argmin from packed key (exact lex winner) ----
        if (tid < Vp)
            idx_arr[tid] = (int)(keysPrev[((size_t)tid << 6) + b] & 0xffffffffu);
        __syncthreads();
        // ---- P3: gather h slice ----
        for (int t = tid; t < Vp*4; t += 256)
            hs[t] = emb[(size_t)idx_arr[t >> 2]*32 + c0 + (t & 3)];
        // ---- P4: bicubic weights in fp64 exactly like jax ----
        if (tid < 16) {
            double scl = 16.0 / (double)pnPrev;
            double inv = 1.0 / scl;
            double sp = ((double)tid + 0.5) * inv - 0.5;
            double w64[16]; double tot = 0.0;
            for (int q = 0; q < pnPrev; ++q) {
                double wv = keys64(fabs(sp - (double)q));
                w64[q] = wv; tot += wv;
            }
            for (int q = 0; q < pnPrev; ++q) U[tid*16 + q] = (float)(w64[q] / tot);
        }
        __syncthreads();
        // ---- P5: windowed bicubic apply, 1 thread per yx, 4 channels. ----
        {
            const double inv = 1.0 / (16.0 / (double)pnPrev);
            const int yx = tid, y = yx >> 4, x = yx & 15;
            double sy = ((double)y + 0.5) * inv - 0.5;
            double sx = ((double)x + 0.5) * inv - 0.5;
            int p0 = (int)floor(sy) - 1, q0 = (int)floor(sx) - 1;
            int pa = max(0, p0), pb = min(pnPrev - 1, p0 + 3);
            int qa = max(0, q0), qb = min(pnPrev - 1, q0 + 3);
            float acc0 = 0.f, acc1 = 0.f, acc2 = 0.f, acc3 = 0.f;
            for (int p = pa; p <= pb; ++p) {
                float wy = U[y*16 + p];
                for (int q = qa; q <= qb; ++q) {
                    float wx = U[x*16 + q];
                    const float* hp = &hs[(p*pnPrev + q)*4];
                    acc0 = __fadd_rn(acc0, __fmul_rn(__fmul_rn(hp[0], wy), wx));
                    acc1 = __fadd_rn(acc1, __fmul_rn(__fmul_rn(hp[1], wy), wx));
                    acc2 = __fadd_rn(acc2, __fmul_rn(__fmul_rn(hp[2], wy), wx));
                    acc3 = __fadd_rn(acc3, __fmul_rn(__fmul_rn(hp[3], wy), wx));
                }
            }
            float a4[4] = {acc0, acc1, acc2, acc3};
            #pragma unroll
            for (int cc = 0; cc < 4; ++cc) {
                float frv = __fsub_rn(fr[yx*5 + cc], a4[cc]);
                fr[yx*5 + cc] = frv;
                int go = b*8192 + (c0 + cc)*256 + yx;
                state[go] = frv;
                fhat[go] = (sIdx == 1) ? a4[cc] : __fadd_rn(fhat[go], a4[cc]);
            }
        }
        __syncthreads();
    }

    // ---- P7: area pool (np einsum order: fl(coef*f), h outer, w inner) + z write ----
    const int V = pn * pn;
    if (pn < 16) {
        if (tid < V) {
            int p = tid / pn, q = tid - p*pn;
            int sh = (p*16)/pn, eh = ((p+1)*16 + pn - 1)/pn;
            int sw = (q*16)/pn, ew = ((q+1)*16 + pn - 1)/pn;
            float Mh = (float)(1.0/(double)(eh - sh));
            float Mw = (float)(1.0/(double)(ew - sw));
            float coef = __fmul_rn(Mh, Mw);
            float a4[4] = {0.f, 0.f, 0.f, 0.f};
            for (int hh = sh; hh < eh; ++hh)
                for (int wy = sw; wy < ew; ++wy) {
                    const float* fp = &fr[(hh*16 + wy)*5];
                    #pragma unroll
                    for (int cc = 0; cc < 4; ++cc)
                        a4[cc] = __fadd_rn(a4[cc], __fmul_rn(coef, fp[cc]));
                }
            *(float4*)(zws + (size_t)((tid << 6) + b)*32 + c0) =
                make_float4(a4[0], a4[1], a4[2], a4[3]);
        }
    } else {
        const int yx = tid;
        *(float4*)(zws + (size_t)((yx << 6) + b)*32 + c0) =
            make_float4(fr[yx*5], fr[yx*5 + 1], fr[yx*5 + 2], fr[yx*5 + 3]);
    }
}

// ---------------- scan: SGPR emb rows, 2 pairs/lane, atomic lex-min merge ---
// Round-10 kernel with two changes, both motivated by round-10 counters:
//  1. STAGGERED atomic write order: with &-decode, concurrently-running WGs
//     share pblk (consecutive ids) -> they all atomicMin the SAME 128 keys
//     (16 cachelines) at WG end -> cross-XCD line ping-pong (round-10 total
//     regressed 368->383 despite faster scan interior). Thread tid now
//     handles t2 = (tid + cb*8) & 127 — bijective, identical atomic set,
//     but concurrent chunk-WGs start on different cachelines.
//  2. NC retuned up at the big scales (s6..s9: 128/64/64/32): atomic merge
//     makes WG count free; smaller CB halves per-WG runtime -> finer grid
//     quantization -> less tail waste (big scan showed ~2.5 effective
//     concurrency generations at NC=16).
// Per-WG numerics identical to validated rounds 4/7/8/10: single asm
// statement per 2-code step (4x s_load_dwordx16 + s_load_dwordx2 +
// s_waitcnt lgkmcnt(0); no scalar DMA outlives its statement), per-wave
// ascending j, 4-wave (d,j)-lex LDS reduce, exact mono-key u64 atomicMin.
typedef float f32x16 __attribute__((ext_vector_type(16)));
typedef float f32x2  __attribute__((ext_vector_type(2)));

#define SLOADW2(E0, E1, F0, F1, Q2, JS) { \
    const float* _pe = emb + ((size_t)(JS) << 5); \
    const float* _pq = esq + (JS); \
    asm volatile("s_load_dwordx16 %0, %5, 0x0\n\t" \
                 "s_load_dwordx16 %1, %5, 0x40\n\t" \
                 "s_load_dwordx16 %2, %5, 0x80\n\t" \
                 "s_load_dwordx16 %3, %5, 0xC0\n\t" \
                 "s_load_dwordx2  %4, %6, 0x0\n\t" \
                 "s_waitcnt lgkmcnt(0)" \
        : "=&s"(E0), "=&s"(E1), "=&s"(F0), "=&s"(F1), "=&s"(Q2) \
        : "s"(_pe), "s"(_pq)); }

#define DOT4S(EV, K, ZA, ZB) { \
    const float ex_ = EV[4*(K)+0], ey_ = EV[4*(K)+1]; \
    const float ez_ = EV[4*(K)+2], ew_ = EV[4*(K)+3]; \
    acc0 = __fmaf_rn(ex_, ZA.x, acc0); acc1 = __fmaf_rn(ex_, ZB.x, acc1); \
    acc0 = __fmaf_rn(ey_, ZA.y, acc0); acc1 = __fmaf_rn(ey_, ZB.y, acc1); \
    acc0 = __fmaf_rn(ez_, ZA.z, acc0); acc1 = __fmaf_rn(ez_, ZB.z, acc1); \
    acc0 = __fmaf_rn(ew_, ZA.w, acc0); acc1 = __fmaf_rn(ew_, ZB.w, acc1); }

#define CODE_STEP(E0, E1, SQ, J) { \
    float acc0 = 0.f, acc1 = 0.f; \
    DOT4S(E0, 0, a0, b0) DOT4S(E0, 1, a1, b1) DOT4S(E0, 2, a2, b2) DOT4S(E0, 3, a3, b3) \
    DOT4S(E1, 0, a4, b4) DOT4S(E1, 1, a5, b5) DOT4S(E1, 2, a6, b6) DOT4S(E1, 3, a7, b7) \
    float d0 = __fsub_rn(__fadd_rn(zsq0, SQ), __fmul_rn(2.0f, acc0)); \
    float d1 = __fsub_rn(__fadd_rn(zsq1, SQ), __fmul_rn(2.0f, acc1)); \
    if (d0 < best0) { best0 = d0; bi0 = (J); } \
    if (d1 < best1) { best1 = d1; bi1 = (J); } }

__global__ __launch_bounds__(256, 4) void vq_scan(
    const float* __restrict__ emb, const float* __restrict__ esq,
    const float* __restrict__ zws, unsigned long long* __restrict__ keys,
    int V, int ncMask, int ncShift)
{
    __shared__ float red_f[512];
    __shared__ int   red_i[512];

    const int tid  = threadIdx.x;
    const int cb   = blockIdx.x & ncMask;   // co-resident WGs (ids +-256k) share cb
    const int pblk = blockIdx.x >> ncShift;
    const int w    = tid >> 6, lane = tid & 63;
    const int N    = V << 6;
    const int CB   = 4096 >> ncShift;

    const int pair0 = (pblk << 7) + lane;
    const int p0c = min(pair0, N - 1), p1c = min(pair0 + 64, N - 1);
    const float4* za = (const float4*)(zws + (size_t)p0c*32);
    const float4* zb = (const float4*)(zws + (size_t)p1c*32);
    float4 a0 = za[0], a1 = za[1], a2 = za[2], a3 = za[3];
    float4 a4 = za[4], a5 = za[5], a6 = za[6], a7 = za[7];
    float4 b0 = zb[0], b1 = zb[1], b2 = zb[2], b3 = zb[3];
    float4 b4 = zb[4], b5 = zb[5], b6 = zb[6], b7 = zb[7];
    float zsq0 = np_pw32(v4sq(a0),v4sq(a1),v4sq(a2),v4sq(a3),
                         v4sq(a4),v4sq(a5),v4sq(a6),v4sq(a7));
    float zsq1 = np_pw32(v4sq(b0),v4sq(b1),v4sq(b2),v4sq(b3),
                         v4sq(b4),v4sq(b5),v4sq(b6),v4sq(b7));

    // per-wave contiguous code range: j ascending within wave = first-index
    const int jchunk = cb * CB;
    const int pw     = CB >> 2;                       // codes per wave (even, >=4)
    const int w_u    = __builtin_amdgcn_readfirstlane(w);
    const int jbase  = jchunk + w_u * pw;             // always even

    float best0 = INFINITY, best1 = INFINITY; int bi0 = 0, bi1 = 0;
    for (int i = 0; i < pw; i += 2) {
        const int j = jbase + i;
        f32x16 e0, e1, f0, f1; f32x2 q2;
        SLOADW2(e0, e1, f0, f1, q2, j);
        const float q0 = q2[0], q1 = q2[1];
        CODE_STEP(e0, e1, q0, j);
        CODE_STEP(f0, f1, q1, j + 1);
    }

    red_f[w*128 + lane]      = best0;  red_i[w*128 + lane]      = bi0;
    red_f[w*128 + 64 + lane] = best1;  red_i[w*128 + 64 + lane] = bi1;
    __syncthreads();

    if (tid < 128) {
        // staggered handling order: bijective shift by cb spreads concurrent
        // chunk-WGs' atomics across different cachelines
        const int t2 = (tid + ((cb & 15) << 3)) & 127;
        const int p = (pblk << 7) + t2;
        if (p < N) {
            float bb = INFINITY; int bi = 0x7fffffff;
            #pragma unroll
            for (int ww = 0; ww < 4; ++ww) {     // wave j-ranges disjoint: (d,j) lex
                float sc = red_f[ww*128 + t2];
                int   ji = red_i[ww*128 + t2];
                if (sc < bb || (sc == bb && ji < bi)) { bb = sc; bi = ji; }
            }
            // exact order-preserving float->u32 map, then (d,j)-lex atomicMin
            unsigned u  = __float_as_uint(bb);
            unsigned mu = (u & 0x80000000u) ? ~u : (u | 0x80000000u);
            unsigned long long key =
                ((unsigned long long)mu << 32) | (unsigned long long)(unsigned)bi;
            atomicMin(&keys[p], key);
        }
    }
}

__global__ __launch_bounds__(256) void vq_final(
    const float* __restrict__ emb, const float* __restrict__ fhat,
    const unsigned long long* __restrict__ keys,
    float* __restrict__ out)
{
    __shared__ int idx_arr[256];
    const int tid = threadIdx.x;
    const int b = blockIdx.x;
    idx_arr[tid] = (int)(keys[((size_t)tid << 6) + b] & 0xffffffffu);
    __syncthreads();
    // out = f_hat + h9 (channel-major matches out BCHW), coalesced
    for (int o = tid; o < 8192; o += 256) {
        int c = o >> 8, yx = o & 255;
        out[b*8192 + o] = __fadd_rn(fhat[(size_t)b*8192 + o],
                                    emb[(size_t)idx_arr[yx]*32 + c]);
    }
}

extern "C" void kernel_launch(void* const* d_in, const int* in_sizes, int n_in,
                              void* d_out, int out_size, void* d_ws, size_t ws_size,
                              hipStream_t stream) {
    const float* f   = (const float*)d_in[0];
    const float* emb = (const float*)d_in[1];
    float* ws  = (float*)d_ws;
    float* out = (float*)d_out;
    float* esq   = ws + WS_ESQ;
    float* state = ws + WS_STATE;
    float* fhatp = ws + WS_FHAT;
    float* zws   = ws + WS_Z;
    unsigned long long* keysA = (unsigned long long*)(ws + WS_PSC);  // [2][16384]
    static const int pns[10] = {1, 2, 3, 4, 5, 6, 8, 10, 13, 16};
    // log2(NC): bigger scales get more, smaller chunks (tail smoothing; the
    // atomic merge makes WG count free). CB = 4096>>nc stays >= 16.
    static const int ncs[10] = {8, 8, 8, 8, 7, 7, 7, 6, 6, 5};

    for (int s = 0; s < 10; ++s) {
        int pn = pns[s], V = pn*pn, sh = ncs[s];
        int PB = ((V << 6) + 127) >> 7;
        unsigned long long* keysCur  = keysA + (size_t)(s & 1) * 16384;
        unsigned long long* keysPrev = keysA + (size_t)((s & 1) ^ 1) * 16384;
        vq_apply<<<(s == 0) ? 528 : 512, 256, 0, stream>>>(
            f, emb, esq, state, fhatp, zws, keysPrev, keysCur,
            s, pn, s > 0 ? pns[s-1] : 0);
        vq_scan<<<PB << sh, 256, 0, stream>>>(emb, esq, zws, keysCur,
                                              V, (1 << sh) - 1, sh);
    }
    vq_final<<<64, 256, 0, stream>>>(emb, fhatp, keysA + 16384, out);
}

// Round 12
// 381.951 us; speedup vs baseline: 1.0776x; 1.0776x over previous
//
#include <hip/hip_runtime.h>
#include <math.h>

// ws layout (floats):
//   esq   : [4096]
//   state : [64*8192]   f_rest, channel-major [b][c][yx]  (== f layout)
//   fhat  : [64*8192]   [b][c][yx]
//   z     : [16384][32] pair=(v<<6|b) rows
//   keys  : [2][16384] u64 (old psc region) — packed (mono(d)<<32)|j per pair
#define WS_ESQ   0
#define WS_STATE 4096
#define WS_FHAT  (4096 + 524288)
#define WS_Z     (4096 + 2*524288)
#define WS_PSC   (4096 + 3*524288)

__device__ __forceinline__ float4 v4add(float4 a, float4 b) {
    return make_float4(__fadd_rn(a.x,b.x), __fadd_rn(a.y,b.y),
                       __fadd_rn(a.z,b.z), __fadd_rn(a.w,b.w));
}
__device__ __forceinline__ float4 v4sq(float4 a) {
    return make_float4(__fmul_rn(a.x,a.x), __fmul_rn(a.y,a.y),
                       __fmul_rn(a.z,a.z), __fmul_rn(a.w,a.w));
}
// numpy pairwise sum of 32 pre-rounded squares held in 8 float4s
__device__ __forceinline__ float np_pw32(float4 q0, float4 q1, float4 q2, float4 q3,
                                         float4 q4, float4 q5, float4 q6, float4 q7) {
    float4 rA = v4add(v4add(v4add(q0, q2), q4), q6);   // r[0..3]
    float4 rB = v4add(v4add(v4add(q1, q3), q5), q7);   // r[4..7]
    float l = __fadd_rn(__fadd_rn(rA.x, rA.y), __fadd_rn(rA.z, rA.w));
    float h = __fadd_rn(__fadd_rn(rB.x, rB.y), __fadd_rn(rB.z, rB.w));
    return __fadd_rn(l, h);
}

__device__ __forceinline__ double keys64(double x) {
    // jax keys cubic (a=-0.5)
    if (x < 1.0)      return ((1.5*x - 2.5)*x)*x + 1.0;
    else if (x < 2.0) return ((-0.5*x + 2.5)*x - 4.0)*x + 2.0;
    return 0.0;
}

// Apply kernel: 512 WGs = 64 b x 8 channel-slices of 4 (+16 esq WGs at s0).
// Prev-scale argmin read straight from the packed atomic key (low 32 bits).
// Slice-0 WGs init THIS scale's key buffer (double-buffered by s&1).
// All fp32 sequences (bicubic, pool) bit-identical to the validated kernel.
__global__ __launch_bounds__(256) void vq_apply(
    const float* __restrict__ f, const float* __restrict__ emb,
    float* __restrict__ esq, float* __restrict__ state, float* __restrict__ fhat,
    float* __restrict__ zws, const unsigned long long* __restrict__ keysPrev,
    unsigned long long* __restrict__ keysCur,
    int sIdx, int pn, int pnPrev)
{
    __shared__ float fr[1280];      // f_rest slice [yx*5+cc]
    __shared__ float hs[676];       // h slice [v*4+cc]
    __shared__ int   idx_arr[176];
    __shared__ float U[256];        // bicubic weights [out][in], fp64->fp32 like jax

    const int tid = threadIdx.x;
    const int wg  = blockIdx.x;
    if (wg >= 512) {                // s0 only: esq WGs
        int j = ((wg - 512) << 8) + tid;
        const float4* e4 = (const float4*)(emb + (size_t)j*32);
        esq[j] = np_pw32(v4sq(e4[0]),v4sq(e4[1]),v4sq(e4[2]),v4sq(e4[3]),
                         v4sq(e4[4]),v4sq(e4[5]),v4sq(e4[6]),v4sq(e4[7]));
        return;
    }
    const int b  = wg >> 3;
    const int c0 = (wg & 7) * 4;

    // init this scale's keys (slice-0 WG per b); scan launches after apply.
    if ((wg & 7) == 0) {
        const int V = pn * pn;
        for (int v = tid; v < V; v += 256) keysCur[(v << 6) + b] = ~0ull;
    }

    // ---- P1: load f_rest slice (channel-major, coalesced) ----
    const float* src = (sIdx <= 1) ? f : state;      // s0 never writes state: same layout
    for (int o = tid; o < 1024; o += 256) {
        int cc = o >> 8, yx = o & 255;
        fr[yx*5 + cc] = src[b*8192 + (c0 + cc)*256 + yx];
    }
    __syncthreads();

    if (sIdx > 0) {
        const int Vp = pnPrev * pnPrev;
        // ---- P2: read prev argmin from packed key (exact lex winner) ----
        if (tid < Vp)
            idx_arr[tid] = (int)(keysPrev[((size_t)tid << 6) + b] & 0xffffffffu);
        __syncthreads();
        // ---- P3: gather h slice ----
        for (int t = tid; t < Vp*4; t += 256)
            hs[t] = emb[(size_t)idx_arr[t >> 2]*32 + c0 + (t & 3)];
        // ---- P4: bicubic weights in fp64 exactly like jax ----
        if (tid < 16) {
            double scl = 16.0 / (double)pnPrev;
            double inv = 1.0 / scl;
            double sp = ((double)tid + 0.5) * inv - 0.5;
            double w64[16]; double tot = 0.0;
            for (int q = 0; q < pnPrev; ++q) {
                double wv = keys64(fabs(sp - (double)q));
                w64[q] = wv; tot += wv;
            }
            for (int q = 0; q < pnPrev; ++q) U[tid*16 + q] = (float)(w64[q] / tot);
        }
        __syncthreads();
        // ---- P5: windowed bicubic apply, 1 thread per yx, 4 channels. ----
        {
            const double inv = 1.0 / (16.0 / (double)pnPrev);
            const int yx = tid, y = yx >> 4, x = yx & 15;
            double sy = ((double)y + 0.5) * inv - 0.5;
            double sx = ((double)x + 0.5) * inv - 0.5;
            int p0 = (int)floor(sy) - 1, q0 = (int)floor(sx) - 1;
            int pa = max(0, p0), pb = min(pnPrev - 1, p0 + 3);
            int qa = max(0, q0), qb = min(pnPrev - 1, q0 + 3);
            float acc0 = 0.f, acc1 = 0.f, acc2 = 0.f, acc3 = 0.f;
            for (int p = pa; p <= pb; ++p) {
                float wy = U[y*16 + p];
                for (int q = qa; q <= qb; ++q) {
                    float wx = U[x*16 + q];
                    const float* hp = &hs[(p*pnPrev + q)*4];
                    acc0 = __fadd_rn(acc0, __fmul_rn(__fmul_rn(hp[0], wy), wx));
                    acc1 = __fadd_rn(acc1, __fmul_rn(__fmul_rn(hp[1], wy), wx));
                    acc2 = __fadd_rn(acc2, __fmul_rn(__fmul_rn(hp[2], wy), wx));
                    acc3 = __fadd_rn(acc3, __fmul_rn(__fmul_rn(hp[3], wy), wx));
                }
            }
            float a4[4] = {acc0, acc1, acc2, acc3};
            #pragma unroll
            for (int cc = 0; cc < 4; ++cc) {
                float frv = __fsub_rn(fr[yx*5 + cc], a4[cc]);
                fr[yx*5 + cc] = frv;
                int go = b*8192 + (c0 + cc)*256 + yx;
                state[go] = frv;
                fhat[go] = (sIdx == 1) ? a4[cc] : __fadd_rn(fhat[go], a4[cc]);
            }
        }
        __syncthreads();
    }

    // ---- P7: area pool (np einsum order: fl(coef*f), h outer, w inner) + z write ----
    const int V = pn * pn;
    if (pn < 16) {
        if (tid < V) {
            int p = tid / pn, q = tid - p*pn;
            int sh = (p*16)/pn, eh = ((p+1)*16 + pn - 1)/pn;
            int sw = (q*16)/pn, ew = ((q+1)*16 + pn - 1)/pn;
            float Mh = (float)(1.0/(double)(eh - sh));
            float Mw = (float)(1.0/(double)(ew - sw));
            float coef = __fmul_rn(Mh, Mw);
            float a4[4] = {0.f, 0.f, 0.f, 0.f};
            for (int hh = sh; hh < eh; ++hh)
                for (int wy = sw; wy < ew; ++wy) {
                    const float* fp = &fr[(hh*16 + wy)*5];
                    #pragma unroll
                    for (int cc = 0; cc < 4; ++cc)
                        a4[cc] = __fadd_rn(a4[cc], __fmul_rn(coef, fp[cc]));
                }
            *(float4*)(zws + (size_t)((tid << 6) + b)*32 + c0) =
                make_float4(a4[0], a4[1], a4[2], a4[3]);
        }
    } else {
        const int yx = tid;
        *(float4*)(zws + (size_t)((yx << 6) + b)*32 + c0) =
            make_float4(fr[yx*5], fr[yx*5 + 1], fr[yx*5 + 2], fr[yx*5 + 3]);
    }
}

// ---------------- scan: SGPR emb rows, 2 pairs/lane, atomic lex-min merge ---
// ROUND-8 CONFIGURATION VERBATIM — best validated (368.4 us total, big scan
// 62.1 us). The surrounding parameter space is a measured local optimum:
//   pairs/lane 4 / 1: -3 / -28 us (R5/R6); deeper SGPR pipeline: corrupt/
//   crash (SMEM returns out of order -> only lgkmcnt(0) safe; 2 buffers
//   exceed the 102-SGPR budget, R1/R2); VMEM e-path: -324 us (spill, R9);
//   cb-major / &-decode: 0 / -14 us (R7/R10); finer chunks + stagger:
//   -29 us (R11). Structural floor: per 2-code step ~280cy VALU + ~120-200cy
//   un-hideable scalar wait at ~3 WGs/CU (4-wave x 112-SGPR footprint).
// Per-WG numerics: single asm statement per 2-code step (4x s_load_dwordx16
// + s_load_dwordx2 + s_waitcnt lgkmcnt(0); no scalar DMA outlives its
// statement), per-wave ascending j (strict <, j before j+1), 4-wave
// (d,j)-lex LDS reduce, exact mono-key u64 atomicMin merge.
typedef float f32x16 __attribute__((ext_vector_type(16)));
typedef float f32x2  __attribute__((ext_vector_type(2)));

#define SLOADW2(E0, E1, F0, F1, Q2, JS) { \
    const float* _pe = emb + ((size_t)(JS) << 5); \
    const float* _pq = esq + (JS); \
    asm volatile("s_load_dwordx16 %0, %5, 0x0\n\t" \
                 "s_load_dwordx16 %1, %5, 0x40\n\t" \
                 "s_load_dwordx16 %2, %5, 0x80\n\t" \
                 "s_load_dwordx16 %3, %5, 0xC0\n\t" \
                 "s_load_dwordx2  %4, %6, 0x0\n\t" \
                 "s_waitcnt lgkmcnt(0)" \
        : "=&s"(E0), "=&s"(E1), "=&s"(F0), "=&s"(F1), "=&s"(Q2) \
        : "s"(_pe), "s"(_pq)); }

#define DOT4S(EV, K, ZA, ZB) { \
    const float ex_ = EV[4*(K)+0], ey_ = EV[4*(K)+1]; \
    const float ez_ = EV[4*(K)+2], ew_ = EV[4*(K)+3]; \
    acc0 = __fmaf_rn(ex_, ZA.x, acc0); acc1 = __fmaf_rn(ex_, ZB.x, acc1); \
    acc0 = __fmaf_rn(ey_, ZA.y, acc0); acc1 = __fmaf_rn(ey_, ZB.y, acc1); \
    acc0 = __fmaf_rn(ez_, ZA.z, acc0); acc1 = __fmaf_rn(ez_, ZB.z, acc1); \
    acc0 = __fmaf_rn(ew_, ZA.w, acc0); acc1 = __fmaf_rn(ew_, ZB.w, acc1); }

#define CODE_STEP(E0, E1, SQ, J) { \
    float acc0 = 0.f, acc1 = 0.f; \
    DOT4S(E0, 0, a0, b0) DOT4S(E0, 1, a1, b1) DOT4S(E0, 2, a2, b2) DOT4S(E0, 3, a3, b3) \
    DOT4S(E1, 0, a4, b4) DOT4S(E1, 1, a5, b5) DOT4S(E1, 2, a6, b6) DOT4S(E1, 3, a7, b7) \
    float d0 = __fsub_rn(__fadd_rn(zsq0, SQ), __fmul_rn(2.0f, acc0)); \
    float d1 = __fsub_rn(__fadd_rn(zsq1, SQ), __fmul_rn(2.0f, acc1)); \
    if (d0 < best0) { best0 = d0; bi0 = (J); } \
    if (d1 < best1) { best1 = d1; bi1 = (J); } }

__global__ __launch_bounds__(256, 4) void vq_scan(
    const float* __restrict__ emb, const float* __restrict__ esq,
    const float* __restrict__ zws, unsigned long long* __restrict__ keys,
    int V, int ncMask, int ncShift)
{
    __shared__ float red_f[512];
    __shared__ int   red_i[512];

    const int tid  = threadIdx.x;
    const int cb   = blockIdx.x & ncMask;
    const int pblk = blockIdx.x >> ncShift;
    const int w    = tid >> 6, lane = tid & 63;
    const int N    = V << 6;
    const int CB   = 4096 >> ncShift;

    const int pair0 = (pblk << 7) + lane;
    const int p0c = min(pair0, N - 1), p1c = min(pair0 + 64, N - 1);
    const float4* za = (const float4*)(zws + (size_t)p0c*32);
    const float4* zb = (const float4*)(zws + (size_t)p1c*32);
    float4 a0 = za[0], a1 = za[1], a2 = za[2], a3 = za[3];
    float4 a4 = za[4], a5 = za[5], a6 = za[6], a7 = za[7];
    float4 b0 = zb[0], b1 = zb[1], b2 = zb[2], b3 = zb[3];
    float4 b4 = zb[4], b5 = zb[5], b6 = zb[6], b7 = zb[7];
    float zsq0 = np_pw32(v4sq(a0),v4sq(a1),v4sq(a2),v4sq(a3),
                         v4sq(a4),v4sq(a5),v4sq(a6),v4sq(a7));
    float zsq1 = np_pw32(v4sq(b0),v4sq(b1),v4sq(b2),v4sq(b3),
                         v4sq(b4),v4sq(b5),v4sq(b6),v4sq(b7));

    // per-wave contiguous code range: j ascending within wave = first-index
    const int jchunk = cb * CB;
    const int pw     = CB >> 2;                       // codes per wave (even, >=4)
    const int w_u    = __builtin_amdgcn_readfirstlane(w);
    const int jbase  = jchunk + w_u * pw;             // always even

    float best0 = INFINITY, best1 = INFINITY; int bi0 = 0, bi1 = 0;
    for (int i = 0; i < pw; i += 2) {
        const int j = jbase + i;
        f32x16 e0, e1, f0, f1; f32x2 q2;
        SLOADW2(e0, e1, f0, f1, q2, j);
        const float q0 = q2[0], q1 = q2[1];
        CODE_STEP(e0, e1, q0, j);
        CODE_STEP(f0, f1, q1, j + 1);
    }

    red_f[w*128 + lane]      = best0;  red_i[w*128 + lane]      = bi0;
    red_f[w*128 + 64 + lane] = best1;  red_i[w*128 + 64 + lane] = bi1;
    __syncthreads();

    if (tid < 128) {
        const int p = (pblk << 7) + tid;
        if (p < N) {
            float bb = INFINITY; int bi = 0x7fffffff;
            #pragma unroll
            for (int ww = 0; ww < 4; ++ww) {     // wave j-ranges disjoint: (d,j) lex
                float sc = red_f[ww*128 + tid];
                int   ji = red_i[ww*128 + tid];
                if (sc < bb || (sc == bb && ji < bi)) { bb = sc; bi = ji; }
            }
            // exact order-preserving float->u32 map, then (d,j)-lex atomicMin
            unsigned u  = __float_as_uint(bb);
            unsigned mu = (u & 0x80000000u) ? ~u : (u | 0x80000000u);
            unsigned long long key =
                ((unsigned long long)mu << 32) | (unsigned long long)(unsigned)bi;
            atomicMin(&keys[p], key);
        }
    }
}

__global__ __launch_bounds__(256) void vq_final(
    const float* __restrict__ emb, const float* __restrict__ fhat,
    const unsigned long long* __restrict__ keys,
    float* __restrict__ out)
{
    __shared__ int idx_arr[256];
    const int tid = threadIdx.x;
    const int b = blockIdx.x;
    idx_arr[tid] = (int)(keys[((size_t)tid << 6) + b] & 0xffffffffu);
    __syncthreads();
    // out = f_hat + h9 (channel-major matches out BCHW), coalesced
    for (int o = tid; o < 8192; o += 256) {
        int c = o >> 8, yx = o & 255;
        out[b*8192 + o] = __fadd_rn(fhat[(size_t)b*8192 + o],
                                    emb[(size_t)idx_arr[yx]*32 + c]);
    }
}

extern "C" void kernel_launch(void* const* d_in, const int* in_sizes, int n_in,
                              void* d_out, int out_size, void* d_ws, size_t ws_size,
                              hipStream_t stream) {
    const float* f   = (const float*)d_in[0];
    const float* emb = (const float*)d_in[1];
    float* ws  = (float*)d_ws;
    float* out = (float*)d_out;
    float* esq   = ws + WS_ESQ;
    float* state = ws + WS_STATE;
    float* fhatp = ws + WS_FHAT;
    float* zws   = ws + WS_Z;
    unsigned long long* keysA = (unsigned long long*)(ws + WS_PSC);  // [2][16384]
    static const int pns[10] = {1, 2, 3, 4, 5, 6, 8, 10, 13, 16};
    static const int ncs[10] = {8, 8, 8, 8, 7, 7, 6, 5, 5, 4};  // log2(NC), CB=4096>>nc

    for (int s = 0; s < 10; ++s) {
        int pn = pns[s], V = pn*pn, sh = ncs[s];
        int PB = ((V << 6) + 127) >> 7;
        unsigned long long* keysCur  = keysA + (size_t)(s & 1) * 16384;
        unsigned long long* keysPrev = keysA + (size_t)((s & 1) ^ 1) * 16384;
        vq_apply<<<(s == 0) ? 528 : 512, 256, 0, stream>>>(
            f, emb, esq, state, fhatp, zws, keysPrev, keysCur,
            s, pn, s > 0 ? pns[s-1] : 0);
        vq_scan<<<PB << sh, 256, 0, stream>>>(emb, esq, zws, keysCur,
                                              V, (1 << sh) - 1, sh);
    }
    vq_final<<<64, 256, 0, stream>>>(emb, fhatp, keysA + 16384, out);
}

// Round 13
// 367.879 us; speedup vs baseline: 1.1188x; 1.0382x over previous
//
#include <hip/hip_runtime.h>
#include <math.h>

// ws layout (floats):
//   esq   : [4096]
//   state : [64*8192]   f_rest, channel-major [b][c][yx]  (== f layout)
//   fhat  : [64*8192]   [b][c][yx]
//   z     : [16384][32] pair=(v<<6|b) rows
//   keys  : [2][16384] u64 (old psc region) — packed (mono(d)<<32)|j per pair
#define WS_ESQ   0
#define WS_STATE 4096
#define WS_FHAT  (4096 + 524288)
#define WS_Z     (4096 + 2*524288)
#define WS_PSC   (4096 + 3*524288)

__device__ __forceinline__ float4 v4add(float4 a, float4 b) {
    return make_float4(__fadd_rn(a.x,b.x), __fadd_rn(a.y,b.y),
                       __fadd_rn(a.z,b.z), __fadd_rn(a.w,b.w));
}
__device__ __forceinline__ float4 v4sq(float4 a) {
    return make_float4(__fmul_rn(a.x,a.x), __fmul_rn(a.y,a.y),
                       __fmul_rn(a.z,a.z), __fmul_rn(a.w,a.w));
}
// numpy pairwise sum of 32 pre-rounded squares held in 8 float4s
__device__ __forceinline__ float np_pw32(float4 q0, float4 q1, float4 q2, float4 q3,
                                         float4 q4, float4 q5, float4 q6, float4 q7) {
    float4 rA = v4add(v4add(v4add(q0, q2), q4), q6);   // r[0..3]
    float4 rB = v4add(v4add(v4add(q1, q3), q5), q7);   // r[4..7]
    float l = __fadd_rn(__fadd_rn(rA.x, rA.y), __fadd_rn(rA.z, rA.w));
    float h = __fadd_rn(__fadd_rn(rB.x, rB.y), __fadd_rn(rB.z, rB.w));
    return __fadd_rn(l, h);
}

__device__ __forceinline__ double keys64(double x) {
    // jax keys cubic (a=-0.5)
    if (x < 1.0)      return ((1.5*x - 2.5)*x)*x + 1.0;
    else if (x < 2.0) return ((-0.5*x + 2.5)*x - 4.0)*x + 2.0;
    return 0.0;
}

// Apply kernel: 512 WGs = 64 b x 8 channel-slices of 4 (+16 esq WGs at s0).
// Prev-scale argmin read straight from the packed atomic key (low 32 bits).
// Slice-0 WGs init THIS scale's key buffer (double-buffered by s&1).
// All fp32 sequences (bicubic, pool) bit-identical to the validated kernel.
__global__ __launch_bounds__(256) void vq_apply(
    const float* __restrict__ f, const float* __restrict__ emb,
    float* __restrict__ esq, float* __restrict__ state, float* __restrict__ fhat,
    float* __restrict__ zws, const unsigned long long* __restrict__ keysPrev,
    unsigned long long* __restrict__ keysCur,
    int sIdx, int pn, int pnPrev)
{
    __shared__ float fr[1280];      // f_rest slice [yx*5+cc]
    __shared__ float hs[676];       // h slice [v*4+cc]
    __shared__ int   idx_arr[176];
    __shared__ float U[256];        // bicubic weights [out][in], fp64->fp32 like jax

    const int tid = threadIdx.x;
    const int wg  = blockIdx.x;
    if (wg >= 512) {                // s0 only: esq WGs
        int j = ((wg - 512) << 8) + tid;
        const float4* e4 = (const float4*)(emb + (size_t)j*32);
        esq[j] = np_pw32(v4sq(e4[0]),v4sq(e4[1]),v4sq(e4[2]),v4sq(e4[3]),
                         v4sq(e4[4]),v4sq(e4[5]),v4sq(e4[6]),v4sq(e4[7]));
        return;
    }
    const int b  = wg >> 3;
    const int c0 = (wg & 7) * 4;

    // init this scale's keys (slice-0 WG per b); scan launches after apply.
    if ((wg & 7) == 0) {
        const int V = pn * pn;
        for (int v = tid; v < V; v += 256) keysCur[(v << 6) + b] = ~0ull;
    }

    // ---- P1: load f_rest slice (channel-major, coalesced) ----
    const float* src = (sIdx <= 1) ? f : state;      // s0 never writes state: same layout
    for (int o = tid; o < 1024; o += 256) {
        int cc = o >> 8, yx = o & 255;
        fr[yx*5 + cc] = src[b*8192 + (c0 + cc)*256 + yx];
    }
    __syncthreads();

    if (sIdx > 0) {
        const int Vp = pnPrev * pnPrev;
        // ---- P2: read prev argmin from packed key (exact lex winner) ----
        if (tid < Vp)
            idx_arr[tid] = (int)(keysPrev[((size_t)tid << 6) + b] & 0xffffffffu);
        __syncthreads();
        // ---- P3: gather h slice ----
        for (int t = tid; t < Vp*4; t += 256)
            hs[t] = emb[(size_t)idx_arr[t >> 2]*32 + c0 + (t & 3)];
        // ---- P4: bicubic weights in fp64 exactly like jax ----
        if (tid < 16) {
            double scl = 16.0 / (double)pnPrev;
            double inv = 1.0 / scl;
            double sp = ((double)tid + 0.5) * inv - 0.5;
            double w64[16]; double tot = 0.0;
            for (int q = 0; q < pnPrev; ++q) {
                double wv = keys64(fabs(sp - (double)q));
                w64[q] = wv; tot += wv;
            }
            for (int q = 0; q < pnPrev; ++q) U[tid*16 + q] = (float)(w64[q] / tot);
        }
        __syncthreads();
        // ---- P5: windowed bicubic apply, 1 thread per yx, 4 channels. ----
        {
            const double inv = 1.0 / (16.0 / (double)pnPrev);
            const int yx = tid, y = yx >> 4, x = yx & 15;
            double sy = ((double)y + 0.5) * inv - 0.5;
            double sx = ((double)x + 0.5) * inv - 0.5;
            int p0 = (int)floor(sy) - 1, q0 = (int)floor(sx) - 1;
            int pa = max(0, p0), pb = min(pnPrev - 1, p0 + 3);
            int qa = max(0, q0), qb = min(pnPrev - 1, q0 + 3);
            float acc0 = 0.f, acc1 = 0.f, acc2 = 0.f, acc3 = 0.f;
            for (int p = pa; p <= pb; ++p) {
                float wy = U[y*16 + p];
                for (int q = qa; q <= qb; ++q) {
                    float wx = U[x*16 + q];
                    const float* hp = &hs[(p*pnPrev + q)*4];
                    acc0 = __fadd_rn(acc0, __fmul_rn(__fmul_rn(hp[0], wy), wx));
                    acc1 = __fadd_rn(acc1, __fmul_rn(__fmul_rn(hp[1], wy), wx));
                    acc2 = __fadd_rn(acc2, __fmul_rn(__fmul_rn(hp[2], wy), wx));
                    acc3 = __fadd_rn(acc3, __fmul_rn(__fmul_rn(hp[3], wy), wx));
                }
            }
            float a4[4] = {acc0, acc1, acc2, acc3};
            #pragma unroll
            for (int cc = 0; cc < 4; ++cc) {
                float frv = __fsub_rn(fr[yx*5 + cc], a4[cc]);
                fr[yx*5 + cc] = frv;
                int go = b*8192 + (c0 + cc)*256 + yx;
                state[go] = frv;
                fhat[go] = (sIdx == 1) ? a4[cc] : __fadd_rn(fhat[go], a4[cc]);
            }
        }
        __syncthreads();
    }

    // ---- P7: area pool (np einsum order: fl(coef*f), h outer, w inner) + z write ----
    const int V = pn * pn;
    if (pn < 16) {
        if (tid < V) {
            int p = tid / pn, q = tid - p*pn;
            int sh = (p*16)/pn, eh = ((p+1)*16 + pn - 1)/pn;
            int sw = (q*16)/pn, ew = ((q+1)*16 + pn - 1)/pn;
            float Mh = (float)(1.0/(double)(eh - sh));
            float Mw = (float)(1.0/(double)(ew - sw));
            float coef = __fmul_rn(Mh, Mw);
            float a4[4] = {0.f, 0.f, 0.f, 0.f};
            for (int hh = sh; hh < eh; ++hh)
                for (int wy = sw; wy < ew; ++wy) {
                    const float* fp = &fr[(hh*16 + wy)*5];
                    #pragma unroll
                    for (int cc = 0; cc < 4; ++cc)
                        a4[cc] = __fadd_rn(a4[cc], __fmul_rn(coef, fp[cc]));
                }
            *(float4*)(zws + (size_t)((tid << 6) + b)*32 + c0) =
                make_float4(a4[0], a4[1], a4[2], a4[3]);
        }
    } else {
        const int yx = tid;
        *(float4*)(zws + (size_t)((yx << 6) + b)*32 + c0) =
            make_float4(fr[yx*5], fr[yx*5 + 1], fr[yx*5 + 2], fr[yx*5 + 3]);
    }
}

// ---------------- scan: SGPR emb rows, 2 pairs/lane, atomic lex-min merge ---
// TRUE ROUND-8 CONFIGURATION (368.4 us total, absmax 7.63e-6) — /PB decode.
// Round-12 accidentally kept round-10's &-decode; counters confirmed it was
// R10's kernel (FETCH 8744 vs R8's 5273, total 382 vs 368). With /PB decode,
// concurrently-dispatched WGs (consecutive ids) share cb and have DISJOINT
// pblk -> their end-of-kernel atomicMins target disjoint key sets (no
// cross-XCD cacheline ping-pong) and zws reads walk adjacent rows (L2
// locality). The &-decode's +4% scan interior never paid for its -6% atomic
// contention (measured twice: R10, R12).
// Per-WG numerics: single asm statement per 2-code step (4x s_load_dwordx16
// + s_load_dwordx2 + s_waitcnt lgkmcnt(0); no scalar DMA outlives its
// statement -> no cross-statement liveness hazards), per-wave ascending j
// (strict <, j before j+1), 4-wave (d,j)-lex LDS reduce, exact mono-key u64
// atomicMin merge. Surrounding parameter space is a measured local optimum:
// pairs/lane 4/1 (R5/R6), deeper SGPR pipeline (R1/R2: SMEM out-of-order ->
// only lgkmcnt(0) safe; dbuf > SGPR budget), VMEM e-path (R9), &-decode
// (R10/R12), finer chunks + stagger (R11) — all regress.
typedef float f32x16 __attribute__((ext_vector_type(16)));
typedef float f32x2  __attribute__((ext_vector_type(2)));

#define SLOADW2(E0, E1, F0, F1, Q2, JS) { \
    const float* _pe = emb + ((size_t)(JS) << 5); \
    const float* _pq = esq + (JS); \
    asm volatile("s_load_dwordx16 %0, %5, 0x0\n\t" \
                 "s_load_dwordx16 %1, %5, 0x40\n\t" \
                 "s_load_dwordx16 %2, %5, 0x80\n\t" \
                 "s_load_dwordx16 %3, %5, 0xC0\n\t" \
                 "s_load_dwordx2  %4, %6, 0x0\n\t" \
                 "s_waitcnt lgkmcnt(0)" \
        : "=&s"(E0), "=&s"(E1), "=&s"(F0), "=&s"(F1), "=&s"(Q2) \
        : "s"(_pe), "s"(_pq)); }

#define DOT4S(EV, K, ZA, ZB) { \
    const float ex_ = EV[4*(K)+0], ey_ = EV[4*(K)+1]; \
    const float ez_ = EV[4*(K)+2], ew_ = EV[4*(K)+3]; \
    acc0 = __fmaf_rn(ex_, ZA.x, acc0); acc1 = __fmaf_rn(ex_, ZB.x, acc1); \
    acc0 = __fmaf_rn(ey_, ZA.y, acc0); acc1 = __fmaf_rn(ey_, ZB.y, acc1); \
    acc0 = __fmaf_rn(ez_, ZA.z, acc0); acc1 = __fmaf_rn(ez_, ZB.z, acc1); \
    acc0 = __fmaf_rn(ew_, ZA.w, acc0); acc1 = __fmaf_rn(ew_, ZB.w, acc1); }

#define CODE_STEP(E0, E1, SQ, J) { \
    float acc0 = 0.f, acc1 = 0.f; \
    DOT4S(E0, 0, a0, b0) DOT4S(E0, 1, a1, b1) DOT4S(E0, 2, a2, b2) DOT4S(E0, 3, a3, b3) \
    DOT4S(E1, 0, a4, b4) DOT4S(E1, 1, a5, b5) DOT4S(E1, 2, a6, b6) DOT4S(E1, 3, a7, b7) \
    float d0 = __fsub_rn(__fadd_rn(zsq0, SQ), __fmul_rn(2.0f, acc0)); \
    float d1 = __fsub_rn(__fadd_rn(zsq1, SQ), __fmul_rn(2.0f, acc1)); \
    if (d0 < best0) { best0 = d0; bi0 = (J); } \
    if (d1 < best1) { best1 = d1; bi1 = (J); } }

__global__ __launch_bounds__(256, 4) void vq_scan(
    const float* __restrict__ emb, const float* __restrict__ esq,
    const float* __restrict__ zws, unsigned long long* __restrict__ keys,
    int V, int PB, int CB)
{
    __shared__ float red_f[512];
    __shared__ int   red_i[512];

    const int tid  = threadIdx.x;
    const int cb   = blockIdx.x / PB;       // cb-major: concurrent WGs share cb,
    const int pblk = blockIdx.x - cb * PB;  // disjoint pblk -> disjoint atomics
    const int w    = tid >> 6, lane = tid & 63;
    const int N    = V << 6;

    const int pair0 = (pblk << 7) + lane;
    const int p0c = min(pair0, N - 1), p1c = min(pair0 + 64, N - 1);
    const float4* za = (const float4*)(zws + (size_t)p0c*32);
    const float4* zb = (const float4*)(zws + (size_t)p1c*32);
    float4 a0 = za[0], a1 = za[1], a2 = za[2], a3 = za[3];
    float4 a4 = za[4], a5 = za[5], a6 = za[6], a7 = za[7];
    float4 b0 = zb[0], b1 = zb[1], b2 = zb[2], b3 = zb[3];
    float4 b4 = zb[4], b5 = zb[5], b6 = zb[6], b7 = zb[7];
    float zsq0 = np_pw32(v4sq(a0),v4sq(a1),v4sq(a2),v4sq(a3),
                         v4sq(a4),v4sq(a5),v4sq(a6),v4sq(a7));
    float zsq1 = np_pw32(v4sq(b0),v4sq(b1),v4sq(b2),v4sq(b3),
                         v4sq(b4),v4sq(b5),v4sq(b6),v4sq(b7));

    // per-wave contiguous code range: j ascending within wave = first-index
    const int jchunk = cb * CB;
    const int pw     = CB >> 2;                       // codes per wave (even, >=4)
    const int w_u    = __builtin_amdgcn_readfirstlane(w);
    const int jbase  = jchunk + w_u * pw;             // always even

    float best0 = INFINITY, best1 = INFINITY; int bi0 = 0, bi1 = 0;
    for (int i = 0; i < pw; i += 2) {
        const int j = jbase + i;
        f32x16 e0, e1, f0, f1; f32x2 q2;
        SLOADW2(e0, e1, f0, f1, q2, j);
        const float q0 = q2[0], q1 = q2[1];
        CODE_STEP(e0, e1, q0, j);
        CODE_STEP(f0, f1, q1, j + 1);
    }

    red_f[w*128 + lane]      = best0;  red_i[w*128 + lane]      = bi0;
    red_f[w*128 + 64 + lane] = best1;  red_i[w*128 + 64 + lane] = bi1;
    __syncthreads();

    if (tid < 128) {
        const int p = (pblk << 7) + tid;
        if (p < N) {
            float bb = INFINITY; int bi = 0x7fffffff;
            #pragma unroll
            for (int ww = 0; ww < 4; ++ww) {     // wave j-ranges disjoint: (d,j) lex
                float sc = red_f[ww*128 + tid];
                int   ji = red_i[ww*128 + tid];
                if (sc < bb || (sc == bb && ji < bi)) { bb = sc; bi = ji; }
            }
            // exact order-preserving float->u32 map, then (d,j)-lex atomicMin
            unsigned u  = __float_as_uint(bb);
            unsigned mu = (u & 0x80000000u) ? ~u : (u | 0x80000000u);
            unsigned long long key =
                ((unsigned long long)mu << 32) | (unsigned long long)(unsigned)bi;
            atomicMin(&keys[p], key);
        }
    }
}

__global__ __launch_bounds__(256) void vq_final(
    const float* __restrict__ emb, const float* __restrict__ fhat,
    const unsigned long long* __restrict__ keys,
    float* __restrict__ out)
{
    __shared__ int idx_arr[256];
    const int tid = threadIdx.x;
    const int b = blockIdx.x;
    idx_arr[tid] = (int)(keys[((size_t)tid << 6) + b] & 0xffffffffu);
    __syncthreads();
    // out = f_hat + h9 (channel-major matches out BCHW), coalesced
    for (int o = tid; o < 8192; o += 256) {
        int c = o >> 8, yx = o & 255;
        out[b*8192 + o] = __fadd_rn(fhat[(size_t)b*8192 + o],
                                    emb[(size_t)idx_arr[yx]*32 + c]);
    }
}

extern "C" void kernel_launch(void* const* d_in, const int* in_sizes, int n_in,
                              void* d_out, int out_size, void* d_ws, size_t ws_size,
                              hipStream_t stream) {
    const float* f   = (const float*)d_in[0];
    const float* emb = (const float*)d_in[1];
    float* ws  = (float*)d_ws;
    float* out = (float*)d_out;
    float* esq   = ws + WS_ESQ;
    float* state = ws + WS_STATE;
    float* fhatp = ws + WS_FHAT;
    float* zws   = ws + WS_Z;
    unsigned long long* keysA = (unsigned long long*)(ws + WS_PSC);  // [2][16384]
    static const int pns[10] = {1, 2, 3, 4, 5, 6, 8, 10, 13, 16};
    static const int cbs[10] = {16, 16, 16, 16, 32, 32, 64, 128, 128, 256};

    for (int s = 0; s < 10; ++s) {
        int pn = pns[s], V = pn*pn, CB = cbs[s];
        int NC = 4096 / CB;
        int PB = ((V << 6) + 127) >> 7;
        unsigned long long* keysCur  = keysA + (size_t)(s & 1) * 16384;
        unsigned long long* keysPrev = keysA + (size_t)((s & 1) ^ 1) * 16384;
        vq_apply<<<(s == 0) ? 528 : 512, 256, 0, stream>>>(
            f, emb, esq, state, fhatp, zws, keysPrev, keysCur,
            s, pn, s > 0 ? pns[s-1] : 0);
        vq_scan<<<PB * NC, 256, 0, stream>>>(emb, esq, zws, keysCur, V, PB, CB);
    }
    vq_final<<<64, 256, 0, stream>>>(emb, fhatp, keysA + 16384, out);
}